// Round 1
// baseline (370.183 us; speedup 1.0000x reference)
//
#include <hip/hip_runtime.h>
#include <hip/hip_bf16.h>

#define NT 1024     // tokens (B*S)
#define HD 1024     // hidden
#define ED 1024     // expert inner dim
#define F2D 2048    // 2*E (interleaved gate/up)
#define NEXPERT 16
#define GROWS 2304  // compacted rows (2048) + tile slack
#define ALPHA_C 1.702f
#define LIMIT_C 7.0f

typedef float f32x4 __attribute__((ext_vector_type(4)));
typedef short short8 __attribute__((ext_vector_type(8)));

__device__ __forceinline__ unsigned short f2bf(float x) {
  union { float f; unsigned int u; } v; v.f = x;
  unsigned int r = v.u + 0x7FFFu + ((v.u >> 16) & 1u);
  return (unsigned short)(r >> 16);
}
__device__ __forceinline__ unsigned int pk2(float lo, float hi) {
  return (unsigned int)f2bf(lo) | ((unsigned int)f2bf(hi) << 16);
}
// async global->LDS, 16B per lane; LDS dest = wave-uniform base + lane*16
__device__ __forceinline__ void async16(const void* g, void* l) {
  __builtin_amdgcn_global_load_lds((const __attribute__((address_space(1))) void*)g,
                                   (__attribute__((address_space(3))) void*)l, 16, 0, 0);
}

// ---------------- router: fp32 logits, top-2, softmax; also x -> bf16 ----------------
__global__ __launch_bounds__(64) void k_router(const float* __restrict__ x,
                                               const float* __restrict__ Wg,
                                               const float* __restrict__ bg,
                                               int* __restrict__ cnt,
                                               int* __restrict__ e01,
                                               float* __restrict__ w0f,
                                               float* __restrict__ w1f,
                                               unsigned short* __restrict__ Xbf) {
  const int t = blockIdx.x;
  const int l = threadIdx.x;
  const float4* x4 = (const float4*)(x + (size_t)t * HD);
  // convert this token's row to bf16 (4 float4 per lane)
  for (int i = 0; i < 4; ++i) {
    const int idx = l + 64 * i;
    float4 v = x4[idx];
    unsigned int a = pk2(v.x, v.y);
    unsigned int b = pk2(v.z, v.w);
    unsigned int* dst = (unsigned int*)(Xbf + (size_t)t * HD + idx * 4);
    dst[0] = a; dst[1] = b;
  }
  // logits: lane -> (expert = l&15, quarter = l>>4)
  const int e = l & 15, qq = l >> 4;
  const float4* wg4 = (const float4*)(Wg + (size_t)e * HD);
  float s = 0.f;
  for (int j = 0; j < 64; ++j) {
    const int idx = qq + 4 * j;
    float4 a = x4[idx], b = wg4[idx];
    s += a.x * b.x + a.y * b.y + a.z * b.z + a.w * b.w;
  }
  s += __shfl_xor(s, 16);
  s += __shfl_xor(s, 32);
  const float logit = s + bg[e];  // valid in lanes 0..15
  // top-2 (strict > keeps lowest index, matching jax.lax.top_k tie-break)
  float v0 = -1e30f, v1 = -1e30f; int i0 = 0, i1 = 0;
  for (int k = 0; k < 16; ++k) {
    float lv = __shfl(logit, k);
    if (lv > v0) { v1 = v0; i1 = i0; v0 = lv; i0 = k; }
    else if (lv > v1) { v1 = lv; i1 = k; }
  }
  if (l == 0) {
    float w0 = 1.f / (1.f + __expf(v1 - v0));
    atomicAdd(&cnt[i0], 1);
    atomicAdd(&cnt[i1], 1);
    e01[t] = i0 | (i1 << 8);
    w0f[t] = w0;
    w1f[t] = 1.f - w0;
  }
}

// ---------------- scan counts -> offsets, place tokens into compact lists ----------------
__global__ __launch_bounds__(1024) void k_scan_place(const int* __restrict__ cnt,
                                                     int* __restrict__ off,
                                                     const int* __restrict__ e01,
                                                     const float* __restrict__ w0f,
                                                     const float* __restrict__ w1f,
                                                     int* __restrict__ gtok,
                                                     float* __restrict__ gwt) {
  __shared__ int soff[NEXPERT];
  __shared__ int scur[NEXPERT];
  const int t = threadIdx.x;
  if (t == 0) {
    int a = 0;
    for (int e = 0; e < NEXPERT; ++e) { soff[e] = a; off[e] = a; a += cnt[e]; }
  }
  if (t < NEXPERT) scur[t] = 0;
  __syncthreads();
  const int p = e01[t];
  const int e0 = p & 255, e1 = p >> 8;
  int s0 = atomicAdd(&scur[e0], 1);
  int g0 = soff[e0] + s0;
  gtok[g0] = t; gwt[g0] = w0f[t];
  int s1 = atomicAdd(&scur[e1], 1);
  int g1 = soff[e1] + s1;
  gtok[g1] = t; gwt[g1] = w1f[t];
}

// ---------------- out init: weighted down-proj biases ----------------
__global__ __launch_bounds__(256) void k_outinit(const float* __restrict__ bd,
                                                 const int* __restrict__ e01,
                                                 const float* __restrict__ w0f,
                                                 const float* __restrict__ w1f,
                                                 float* __restrict__ out) {
  const int t = blockIdx.x;
  const int h4 = threadIdx.x;
  const int p = e01[t];
  const int e0 = p & 255, e1 = p >> 8;
  const float w0 = w0f[t], w1 = w1f[t];
  float4 a = ((const float4*)(bd + (size_t)e0 * HD))[h4];
  float4 b = ((const float4*)(bd + (size_t)e1 * HD))[h4];
  float4 r;
  r.x = w0 * a.x + w1 * b.x;
  r.y = w0 * a.y + w1 * b.y;
  r.z = w0 * a.z + w1 * b.z;
  r.w = w0 * a.w + w1 * b.w;
  ((float4*)(out + (size_t)t * HD))[h4] = r;
}

// ---------------- GEMM1: gathered tokens @ Wgu[e], fused bias+clip+glu, -> Gact bf16 ----------------
__global__ __launch_bounds__(256) void k_gemm1(const unsigned short* __restrict__ Xbf,
                                               const float* __restrict__ Wgu,
                                               const float* __restrict__ bgu,
                                               const int* __restrict__ cnt,
                                               const int* __restrict__ off,
                                               const int* __restrict__ gtok,
                                               unsigned short* __restrict__ Gact) {
  const int e = blockIdx.z;
  const int Ne = cnt[e];
  const int mtile = blockIdx.y;
  if (mtile * 128 >= Ne) return;
  const int ntile = blockIdx.x;            // 16 tiles of 128 f2-cols
  const int tid = threadIdx.x;
  const int lane = tid & 63;
  const int w = tid >> 6;
  const int wm = w & 1, wn = w >> 1;
  const int q = lane >> 4;
  const int fr = lane & 15;

  __shared__ unsigned short Alds[128 * 32];  // (row, k) 64B rows
  __shared__ unsigned int Blds[128 * 17];    // (n, k-pair) 17-dword stride

  const int base = off[e] + mtile * 128;
  // A staging: 2 async16 per thread per k-step; row = w*32 + j*16 + (lane>>2), chunk = lane&3
  const int r0 = w * 32 + (lane >> 2);
  const int r1 = r0 + 16;
  const int c4 = lane & 3;
  const int gs0 = base + (((mtile * 128 + r0) < Ne) ? r0 : 0);
  const int gs1 = base + (((mtile * 128 + r1) < Ne) ? r1 : 0);
  const unsigned short* gp0 = Xbf + (size_t)gtok[gs0] * HD + c4 * 8;
  const unsigned short* gp1 = Xbf + (size_t)gtok[gs1] * HD + c4 * 8;
  unsigned short* la0 = Alds + w * 1024;
  unsigned short* la1 = Alds + w * 1024 + 512;
  // B staging: thread -> (k-pair 2*k2, 8 cols at n8)
  const int k2 = tid >> 4;
  const int n8 = (tid & 15) * 8;
  const float* Wb = Wgu + (size_t)e * HD * F2D + (size_t)(2 * k2) * F2D + ntile * 128 + n8;

  f32x4 acc[4][4] = {};

  for (int ks = 0; ks < 32; ++ks) {
    __syncthreads();
    async16(gp0 + ks * 32, la0);
    async16(gp1 + ks * 32, la1);
    const float* bp = Wb + (size_t)ks * 32 * F2D;
    float4 a0 = *(const float4*)bp;
    float4 a1 = *(const float4*)(bp + 4);
    float4 b0 = *(const float4*)(bp + F2D);
    float4 b1 = *(const float4*)(bp + F2D + 4);
    Blds[(n8 + 0) * 17 + k2] = pk2(a0.x, b0.x);
    Blds[(n8 + 1) * 17 + k2] = pk2(a0.y, b0.y);
    Blds[(n8 + 2) * 17 + k2] = pk2(a0.z, b0.z);
    Blds[(n8 + 3) * 17 + k2] = pk2(a0.w, b0.w);
    Blds[(n8 + 4) * 17 + k2] = pk2(a1.x, b1.x);
    Blds[(n8 + 5) * 17 + k2] = pk2(a1.y, b1.y);
    Blds[(n8 + 6) * 17 + k2] = pk2(a1.z, b1.z);
    Blds[(n8 + 7) * 17 + k2] = pk2(a1.w, b1.w);
    __syncthreads();
    short8 af[4], bfr[4];
#pragma unroll
    for (int ni = 0; ni < 4; ++ni) {
      const unsigned int* p = Blds + (wn * 64 + ni * 16 + fr) * 17 + q * 4;
      union { unsigned int u[4]; short8 s; } uu;
      uu.u[0] = p[0]; uu.u[1] = p[1]; uu.u[2] = p[2]; uu.u[3] = p[3];
      bfr[ni] = uu.s;
    }
#pragma unroll
    for (int mi = 0; mi < 4; ++mi)
      af[mi] = *(const short8*)(Alds + (wm * 64 + mi * 16 + fr) * 32 + q * 8);
#pragma unroll
    for (int mi = 0; mi < 4; ++mi)
#pragma unroll
      for (int ni = 0; ni < 4; ++ni)
        acc[mi][ni] = __builtin_amdgcn_mfma_f32_16x16x32_bf16(af[mi], bfr[ni], acc[mi][ni], 0, 0, 0);
  }

  // epilogue: +bgu, de-interleave gate/up via lane-pair shuffle, activation, store bf16
  const float* bguE = bgu + (size_t)e * F2D + ntile * 128;
#pragma unroll
  for (int mi = 0; mi < 4; ++mi) {
    const int rowb = wm * 64 + mi * 16 + q * 4;
#pragma unroll
    for (int ni = 0; ni < 4; ++ni) {
      const int col = wn * 64 + ni * 16 + fr;
      const float bias = bguE[col];
#pragma unroll
      for (int r = 0; r < 4; ++r) {
        float v = acc[mi][ni][r] + bias;
        float pv = __shfl_xor(v, 1);
        float gate = (lane & 1) ? pv : v;   // even cols are gate, odd are up
        float up   = (lane & 1) ? v : pv;
        gate = fminf(gate, LIMIT_C);
        up = fminf(fmaxf(up, -LIMIT_C), LIMIT_C);
        float glu = gate / (1.f + __expf(-ALPHA_C * gate));
        float val = (up + 1.f) * glu;
        const int s = rowb + r;
        if (!(lane & 1) && (mtile * 128 + s) < Ne)
          Gact[(size_t)(base + s) * ED + ntile * 64 + (col >> 1)] = f2bf(val);
      }
    }
  }
}

// ---------------- GEMM2: Gact @ Wd[e], scaled atomic accumulate into out ----------------
__global__ __launch_bounds__(256) void k_gemm2(const unsigned short* __restrict__ Gact,
                                               const float* __restrict__ Wd,
                                               const int* __restrict__ cnt,
                                               const int* __restrict__ off,
                                               const int* __restrict__ gtok,
                                               const float* __restrict__ gwt,
                                               float* __restrict__ out) {
  const int e = blockIdx.z;
  const int Ne = cnt[e];
  const int mtile = blockIdx.y;
  if (mtile * 128 >= Ne) return;
  const int ntile = blockIdx.x;            // 8 tiles of 128 h-cols
  const int tid = threadIdx.x;
  const int lane = tid & 63;
  const int w = tid >> 6;
  const int wm = w & 1, wn = w >> 1;
  const int q = lane >> 4;
  const int fr = lane & 15;

  __shared__ unsigned short Alds[128 * 32];
  __shared__ unsigned int Blds[128 * 17];

  const int base = off[e] + mtile * 128;
  const int r0 = w * 32 + (lane >> 2);
  const int r1 = r0 + 16;
  const int c4 = lane & 3;
  const unsigned short* gp0 = Gact + (size_t)(base + r0) * ED + c4 * 8;  // slack rows: safe
  const unsigned short* gp1 = Gact + (size_t)(base + r1) * ED + c4 * 8;
  unsigned short* la0 = Alds + w * 1024;
  unsigned short* la1 = Alds + w * 1024 + 512;
  const int k2 = tid >> 4;
  const int n8 = (tid & 15) * 8;
  const float* Wb = Wd + (size_t)e * ED * HD + (size_t)(2 * k2) * HD + ntile * 128 + n8;

  f32x4 acc[4][4] = {};

  for (int ks = 0; ks < 32; ++ks) {
    __syncthreads();
    async16(gp0 + ks * 32, la0);
    async16(gp1 + ks * 32, la1);
    const float* bp = Wb + (size_t)ks * 32 * HD;
    float4 a0 = *(const float4*)bp;
    float4 a1 = *(const float4*)(bp + 4);
    float4 b0 = *(const float4*)(bp + HD);
    float4 b1 = *(const float4*)(bp + HD + 4);
    Blds[(n8 + 0) * 17 + k2] = pk2(a0.x, b0.x);
    Blds[(n8 + 1) * 17 + k2] = pk2(a0.y, b0.y);
    Blds[(n8 + 2) * 17 + k2] = pk2(a0.z, b0.z);
    Blds[(n8 + 3) * 17 + k2] = pk2(a0.w, b0.w);
    Blds[(n8 + 4) * 17 + k2] = pk2(a1.x, b1.x);
    Blds[(n8 + 5) * 17 + k2] = pk2(a1.y, b1.y);
    Blds[(n8 + 6) * 17 + k2] = pk2(a1.z, b1.z);
    Blds[(n8 + 7) * 17 + k2] = pk2(a1.w, b1.w);
    __syncthreads();
    short8 af[4], bfr[4];
#pragma unroll
    for (int ni = 0; ni < 4; ++ni) {
      const unsigned int* p = Blds + (wn * 64 + ni * 16 + fr) * 17 + q * 4;
      union { unsigned int u[4]; short8 s; } uu;
      uu.u[0] = p[0]; uu.u[1] = p[1]; uu.u[2] = p[2]; uu.u[3] = p[3];
      bfr[ni] = uu.s;
    }
#pragma unroll
    for (int mi = 0; mi < 4; ++mi)
      af[mi] = *(const short8*)(Alds + (wm * 64 + mi * 16 + fr) * 32 + q * 8);
#pragma unroll
    for (int mi = 0; mi < 4; ++mi)
#pragma unroll
      for (int ni = 0; ni < 4; ++ni)
        acc[mi][ni] = __builtin_amdgcn_mfma_f32_16x16x32_bf16(af[mi], bfr[ni], acc[mi][ni], 0, 0, 0);
  }

#pragma unroll
  for (int mi = 0; mi < 4; ++mi) {
    const int rowb = wm * 64 + mi * 16 + q * 4;
#pragma unroll
    for (int r = 0; r < 4; ++r) {
      const int s = rowb + r;
      if ((mtile * 128 + s) < Ne) {
        const int gsl = base + s;
        const int tok = gtok[gsl];
        const float wt = gwt[gsl];
        float* op = out + (size_t)tok * HD + ntile * 128;
#pragma unroll
        for (int ni = 0; ni < 4; ++ni) {
          const int col = wn * 64 + ni * 16 + fr;
          atomicAdd(op + col, wt * acc[mi][ni][r]);
        }
      }
    }
  }
}

extern "C" void kernel_launch(void* const* d_in, const int* in_sizes, int n_in,
                              void* d_out, int out_size, void* d_ws, size_t ws_size,
                              hipStream_t stream) {
  const float* x   = (const float*)d_in[0];
  const float* Wg  = (const float*)d_in[1];
  const float* bg  = (const float*)d_in[2];
  const float* Wgu = (const float*)d_in[3];
  const float* bgu = (const float*)d_in[4];
  const float* Wd  = (const float*)d_in[5];
  const float* bd  = (const float*)d_in[6];
  float* out = (float*)d_out;

  int* cnt = (int*)d_ws;                    // 16
  int* off = cnt + 16;                      // 16
  int* e01 = off + 16;                      // 1024
  float* w0f = (float*)(e01 + NT);          // 1024
  float* w1f = w0f + NT;                    // 1024
  int* gtok = (int*)(w1f + NT);             // GROWS
  float* gwt = (float*)(gtok + GROWS);      // GROWS
  unsigned short* Xbf = (unsigned short*)(gwt + GROWS);        // NT*HD bf16
  unsigned short* Gact = Xbf + (size_t)NT * HD;                // GROWS*ED bf16

  hipMemsetAsync(cnt, 0, 16 * sizeof(int), stream);
  k_router<<<NT, 64, 0, stream>>>(x, Wg, bg, cnt, e01, w0f, w1f, Xbf);
  k_scan_place<<<1, NT, 0, stream>>>(cnt, off, e01, w0f, w1f, gtok, gwt);
  k_gemm1<<<dim3(16, 8, NEXPERT), 256, 0, stream>>>(Xbf, Wgu, bgu, cnt, off, gtok, Gact);
  k_outinit<<<NT, 256, 0, stream>>>(bd, e01, w0f, w1f, out);
  k_gemm2<<<dim3(8, 8, NEXPERT), 256, 0, stream>>>(Gact, Wd, cnt, off, gtok, gwt, out);
}

// Round 2
// 345.898 us; speedup vs baseline: 1.0702x; 1.0702x over previous
//
#include <hip/hip_runtime.h>
#include <hip/hip_bf16.h>

#define NT 1024     // tokens (B*S)
#define HD 1024     // hidden
#define ED 1024     // expert inner dim
#define F2D 2048    // 2*E (interleaved gate/up)
#define NEXPERT 16
#define GROWS 2304  // compacted rows (2048) + tile slack
#define ALPHA_C 1.702f
#define LIMIT_C 7.0f

typedef float f32x4 __attribute__((ext_vector_type(4)));
typedef short short8 __attribute__((ext_vector_type(8)));
typedef unsigned int u32x4 __attribute__((ext_vector_type(4)));

__device__ __forceinline__ unsigned short f2bf(float x) {
  union { float f; unsigned int u; } v; v.f = x;
  unsigned int r = v.u + 0x7FFFu + ((v.u >> 16) & 1u);
  return (unsigned short)(r >> 16);
}
__device__ __forceinline__ unsigned int pk2(float lo, float hi) {
  return (unsigned int)f2bf(lo) | ((unsigned int)f2bf(hi) << 16);
}
// async global->LDS, 16B per lane; LDS dest = wave-uniform base + lane*16
__device__ __forceinline__ void async16(const void* g, void* l) {
  __builtin_amdgcn_global_load_lds((const __attribute__((address_space(1))) void*)g,
                                   (__attribute__((address_space(3))) void*)l, 16, 0, 0);
}

// ---------------- router: fp32 logits, top-2, softmax; x->bf16; out = w0*bd[e0]+w1*bd[e1] ----------------
__global__ __launch_bounds__(64) void k_router(const float* __restrict__ x,
                                               const float* __restrict__ Wg,
                                               const float* __restrict__ bg,
                                               const float* __restrict__ bd,
                                               int* __restrict__ e01,
                                               float* __restrict__ w0f,
                                               float* __restrict__ w1f,
                                               unsigned short* __restrict__ Xbf,
                                               float* __restrict__ out) {
  const int t = blockIdx.x;
  const int l = threadIdx.x;
  const float4* x4 = (const float4*)(x + (size_t)t * HD);
  // convert this token's row to bf16 (4 float4 per lane)
  for (int i = 0; i < 4; ++i) {
    const int idx = l + 64 * i;
    float4 v = x4[idx];
    unsigned int a = pk2(v.x, v.y);
    unsigned int b = pk2(v.z, v.w);
    unsigned int* dst = (unsigned int*)(Xbf + (size_t)t * HD + idx * 4);
    dst[0] = a; dst[1] = b;
  }
  // logits: lane -> (expert = l&15, quarter = l>>4)
  const int e = l & 15, qq = l >> 4;
  const float4* wg4 = (const float4*)(Wg + (size_t)e * HD);
  float s = 0.f;
  for (int j = 0; j < 64; ++j) {
    const int idx = qq + 4 * j;
    float4 a = x4[idx], b = wg4[idx];
    s += a.x * b.x + a.y * b.y + a.z * b.z + a.w * b.w;
  }
  s += __shfl_xor(s, 16);
  s += __shfl_xor(s, 32);
  const float logit = s + bg[e];  // valid in lanes 0..15
  // top-2 (strict > keeps lowest index, matching jax.lax.top_k tie-break)
  float v0 = -1e30f, v1 = -1e30f; int i0 = 0, i1 = 0;
  for (int k = 0; k < 16; ++k) {
    float lv = __shfl(logit, k);
    if (lv > v0) { v1 = v0; i1 = i0; v0 = lv; i0 = k; }
    else if (lv > v1) { v1 = lv; i1 = k; }
  }
  const float w0 = 1.f / (1.f + __expf(v1 - v0));
  const float w1 = 1.f - w0;
  if (l == 0) {
    e01[t] = i0 | (i1 << 8);
    w0f[t] = w0;
    w1f[t] = w1;
  }
  // out init: weighted down-proj biases (replaces separate kernel)
  const float4* bd0 = (const float4*)(bd + (size_t)i0 * HD);
  const float4* bd1 = (const float4*)(bd + (size_t)i1 * HD);
  float4* o4 = (float4*)(out + (size_t)t * HD);
  for (int i = 0; i < 4; ++i) {
    const int idx = l + 64 * i;
    float4 a = bd0[idx], b = bd1[idx];
    float4 r;
    r.x = w0 * a.x + w1 * b.x;
    r.y = w0 * a.y + w1 * b.y;
    r.z = w0 * a.z + w1 * b.z;
    r.w = w0 * a.w + w1 * b.w;
    o4[idx] = r;
  }
}

// ---------------- scan: counts, offsets, placement (one block) ----------------
__global__ __launch_bounds__(1024) void k_scan(const int* __restrict__ e01,
                                               const float* __restrict__ w0f,
                                               const float* __restrict__ w1f,
                                               int* __restrict__ cnt,
                                               int* __restrict__ off,
                                               int* __restrict__ gtok,
                                               float* __restrict__ gwt) {
  __shared__ int scnt[NEXPERT];
  __shared__ int soff[NEXPERT];
  __shared__ int scur[NEXPERT];
  const int t = threadIdx.x;
  if (t < NEXPERT) { scnt[t] = 0; scur[t] = 0; }
  __syncthreads();
  const int p = e01[t];
  const int e0 = p & 255, e1 = p >> 8;
  atomicAdd(&scnt[e0], 1);
  atomicAdd(&scnt[e1], 1);
  __syncthreads();
  if (t == 0) {
    int a = 0;
    for (int e = 0; e < NEXPERT; ++e) { soff[e] = a; off[e] = a; cnt[e] = scnt[e]; a += scnt[e]; }
  }
  __syncthreads();
  int s0 = atomicAdd(&scur[e0], 1);
  int g0 = soff[e0] + s0;
  gtok[g0] = t; gwt[g0] = w0f[t];
  int s1 = atomicAdd(&scur[e1], 1);
  int g1 = soff[e1] + s1;
  gtok[g1] = t; gwt[g1] = w1f[t];
}

// ---------------- GEMM1: 128x64 tile, BK=32, double-buffered, 1 barrier/iter ----------------
// grid (32 ntiles, 8 mtiles, 16 experts); Wgu[e] is [K=1024][N=2048]
__global__ __launch_bounds__(256, 4) void k_gemm1(const unsigned short* __restrict__ Xbf,
                                                  const float* __restrict__ Wgu,
                                                  const float* __restrict__ bgu,
                                                  const int* __restrict__ cnt,
                                                  const int* __restrict__ off,
                                                  const int* __restrict__ gtok,
                                                  unsigned short* __restrict__ Gact) {
  const int e = blockIdx.z;
  const int Ne = cnt[e];
  const int mtile = blockIdx.y;
  if (mtile * 128 >= Ne) return;
  const int ntile = blockIdx.x;
  const int tid = threadIdx.x;
  const int lane = tid & 63;
  const int w = tid >> 6;
  const int wm = w & 1, wn = w >> 1;
  const int q = lane >> 4;
  const int fr = lane & 15;

  __shared__ unsigned short Alds[2 * 128 * 32];  // double buffer, (row,k) 64B rows
  __shared__ unsigned int Blds[2 * 16 * 68];     // double buffer, [kpair][n] stride 68 dwords

  const int base = off[e] + mtile * 128;
  const int r0 = w * 32 + (lane >> 2);
  const int r1 = r0 + 16;
  const int c4a = lane & 3;
  const int gs0 = base + (((mtile * 128 + r0) < Ne) ? r0 : 0);
  const int gs1 = base + (((mtile * 128 + r1) < Ne) ? r1 : 0);
  const unsigned short* gp0 = Xbf + (size_t)gtok[gs0] * HD + c4a * 8;
  const unsigned short* gp1 = Xbf + (size_t)gtok[gs1] * HD + c4a * 8;
  const int lofs = w * 1024;  // shorts

  const int k2 = tid >> 4;          // 0..15 kpair
  const int c4 = tid & 15;          // 4-col group
  const float* Wb = Wgu + (size_t)e * HD * F2D + (size_t)(2 * k2) * F2D + ntile * 64 + c4 * 4;

  f32x4 acc[4][2] = {};
  float4 ba, bb;

  // prologue: stage tile 0
  ba = *(const float4*)Wb;
  bb = *(const float4*)(Wb + F2D);
  async16(gp0, Alds + lofs);
  async16(gp1, Alds + lofs + 512);
  {
    u32x4 pkv;
    pkv[0] = pk2(ba.x, bb.x); pkv[1] = pk2(ba.y, bb.y);
    pkv[2] = pk2(ba.z, bb.z); pkv[3] = pk2(ba.w, bb.w);
    *(u32x4*)(Blds + k2 * 68 + c4 * 4) = pkv;
  }
  __syncthreads();

#pragma unroll 2
  for (int ks = 0; ks < 32; ++ks) {
    const int cur = ks & 1, nxt = cur ^ 1;
    const bool more = (ks + 1) < 32;
    if (more) {  // prefetch next tile (regs + async LDS)
      const float* bp = Wb + (size_t)(ks + 1) * 32 * F2D;
      ba = *(const float4*)bp;
      bb = *(const float4*)(bp + F2D);
      async16(gp0 + (ks + 1) * 32, Alds + nxt * 4096 + lofs);
      async16(gp1 + (ks + 1) * 32, Alds + nxt * 4096 + lofs + 512);
    }
    short8 af[4], bfr[2];
#pragma unroll
    for (int mi = 0; mi < 4; ++mi)
      af[mi] = *(const short8*)(Alds + cur * 4096 + (wm * 64 + mi * 16 + fr) * 32 + q * 8);
#pragma unroll
    for (int ni = 0; ni < 2; ++ni) {
      const unsigned int* p = Blds + cur * 1088 + q * 4 * 68 + wn * 32 + ni * 16 + fr;
      union { unsigned int u[4]; short8 s; } uu;
      uu.u[0] = p[0]; uu.u[1] = p[68]; uu.u[2] = p[136]; uu.u[3] = p[204];
      bfr[ni] = uu.s;
    }
#pragma unroll
    for (int mi = 0; mi < 4; ++mi)
#pragma unroll
      for (int ni = 0; ni < 2; ++ni)
        acc[mi][ni] = __builtin_amdgcn_mfma_f32_16x16x32_bf16(af[mi], bfr[ni], acc[mi][ni], 0, 0, 0);
    if (more) {
      u32x4 pkv;
      pkv[0] = pk2(ba.x, bb.x); pkv[1] = pk2(ba.y, bb.y);
      pkv[2] = pk2(ba.z, bb.z); pkv[3] = pk2(ba.w, bb.w);
      *(u32x4*)(Blds + nxt * 1088 + k2 * 68 + c4 * 4) = pkv;
    }
    __syncthreads();
  }

  // epilogue: +bgu, de-interleave gate/up via lane-pair shuffle, activation, store bf16
  const float* bguE = bgu + (size_t)e * F2D + ntile * 64;
#pragma unroll
  for (int mi = 0; mi < 4; ++mi) {
    const int rowb = wm * 64 + mi * 16 + q * 4;
#pragma unroll
    for (int ni = 0; ni < 2; ++ni) {
      const int col = wn * 32 + ni * 16 + fr;
      const float bias = bguE[col];
#pragma unroll
      for (int r = 0; r < 4; ++r) {
        float v = acc[mi][ni][r] + bias;
        float pv = __shfl_xor(v, 1);
        float gate = (lane & 1) ? pv : v;   // even cols are gate, odd are up
        float up   = (lane & 1) ? v : pv;
        gate = fminf(gate, LIMIT_C);
        up = fminf(fmaxf(up, -LIMIT_C), LIMIT_C);
        float glu = gate / (1.f + __expf(-ALPHA_C * gate));
        float val = (up + 1.f) * glu;
        const int s = rowb + r;
        if (!(lane & 1) && (mtile * 128 + s) < Ne)
          Gact[(size_t)(base + s) * ED + ntile * 32 + (col >> 1)] = f2bf(val);
      }
    }
  }
}

// ---------------- GEMM2: 128x64 tile, split-K=2, BK=32, double-buffered ----------------
// grid (16 ntiles, 8 mtiles, 32 = expert*2+ksplit); Wd[e] is [K=1024][N=1024]
__global__ __launch_bounds__(256, 4) void k_gemm2(const unsigned short* __restrict__ Gact,
                                                  const float* __restrict__ Wd,
                                                  const int* __restrict__ cnt,
                                                  const int* __restrict__ off,
                                                  const int* __restrict__ gtok,
                                                  const float* __restrict__ gwt,
                                                  float* __restrict__ out) {
  const int z = blockIdx.z;
  const int e = z >> 1, ksp = z & 1;
  const int Ne = cnt[e];
  const int mtile = blockIdx.y;
  if (mtile * 128 >= Ne) return;
  const int ntile = blockIdx.x;
  const int tid = threadIdx.x;
  const int lane = tid & 63;
  const int w = tid >> 6;
  const int wm = w & 1, wn = w >> 1;
  const int q = lane >> 4;
  const int fr = lane & 15;

  __shared__ unsigned short Alds[2 * 128 * 32];
  __shared__ unsigned int Blds[2 * 16 * 68];

  const int base = off[e] + mtile * 128;
  const int r0 = w * 32 + (lane >> 2);
  const int r1 = r0 + 16;
  const int c4a = lane & 3;
  const unsigned short* gp0 = Gact + (size_t)(base + r0) * ED + ksp * 512 + c4a * 8;  // slack rows safe
  const unsigned short* gp1 = Gact + (size_t)(base + r1) * ED + ksp * 512 + c4a * 8;
  const int lofs = w * 1024;

  const int k2 = tid >> 4;
  const int c4 = tid & 15;
  const float* Wb = Wd + (size_t)e * ED * HD + (size_t)(ksp * 512 + 2 * k2) * HD + ntile * 64 + c4 * 4;

  f32x4 acc[4][2] = {};
  float4 ba, bb;

  ba = *(const float4*)Wb;
  bb = *(const float4*)(Wb + HD);
  async16(gp0, Alds + lofs);
  async16(gp1, Alds + lofs + 512);
  {
    u32x4 pkv;
    pkv[0] = pk2(ba.x, bb.x); pkv[1] = pk2(ba.y, bb.y);
    pkv[2] = pk2(ba.z, bb.z); pkv[3] = pk2(ba.w, bb.w);
    *(u32x4*)(Blds + k2 * 68 + c4 * 4) = pkv;
  }
  __syncthreads();

#pragma unroll 2
  for (int ks = 0; ks < 16; ++ks) {
    const int cur = ks & 1, nxt = cur ^ 1;
    const bool more = (ks + 1) < 16;
    if (more) {
      const float* bp = Wb + (size_t)(ks + 1) * 32 * HD;
      ba = *(const float4*)bp;
      bb = *(const float4*)(bp + HD);
      async16(gp0 + (ks + 1) * 32, Alds + nxt * 4096 + lofs);
      async16(gp1 + (ks + 1) * 32, Alds + nxt * 4096 + lofs + 512);
    }
    short8 af[4], bfr[2];
#pragma unroll
    for (int mi = 0; mi < 4; ++mi)
      af[mi] = *(const short8*)(Alds + cur * 4096 + (wm * 64 + mi * 16 + fr) * 32 + q * 8);
#pragma unroll
    for (int ni = 0; ni < 2; ++ni) {
      const unsigned int* p = Blds + cur * 1088 + q * 4 * 68 + wn * 32 + ni * 16 + fr;
      union { unsigned int u[4]; short8 s; } uu;
      uu.u[0] = p[0]; uu.u[1] = p[68]; uu.u[2] = p[136]; uu.u[3] = p[204];
      bfr[ni] = uu.s;
    }
#pragma unroll
    for (int mi = 0; mi < 4; ++mi)
#pragma unroll
      for (int ni = 0; ni < 2; ++ni)
        acc[mi][ni] = __builtin_amdgcn_mfma_f32_16x16x32_bf16(af[mi], bfr[ni], acc[mi][ni], 0, 0, 0);
    if (more) {
      u32x4 pkv;
      pkv[0] = pk2(ba.x, bb.x); pkv[1] = pk2(ba.y, bb.y);
      pkv[2] = pk2(ba.z, bb.z); pkv[3] = pk2(ba.w, bb.w);
      *(u32x4*)(Blds + nxt * 1088 + k2 * 68 + c4 * 4) = pkv;
    }
    __syncthreads();
  }

#pragma unroll
  for (int mi = 0; mi < 4; ++mi) {
    const int rowb = wm * 64 + mi * 16 + q * 4;
#pragma unroll
    for (int r = 0; r < 4; ++r) {
      const int s = rowb + r;
      if ((mtile * 128 + s) < Ne) {
        const int gsl = base + s;
        const int tok = gtok[gsl];
        const float wt = gwt[gsl];
        float* op = out + (size_t)tok * HD + ntile * 64;
#pragma unroll
        for (int ni = 0; ni < 2; ++ni) {
          const int col = wn * 32 + ni * 16 + fr;
          atomicAdd(op + col, wt * acc[mi][ni][r]);
        }
      }
    }
  }
}

extern "C" void kernel_launch(void* const* d_in, const int* in_sizes, int n_in,
                              void* d_out, int out_size, void* d_ws, size_t ws_size,
                              hipStream_t stream) {
  const float* x   = (const float*)d_in[0];
  const float* Wg  = (const float*)d_in[1];
  const float* bg  = (const float*)d_in[2];
  const float* Wgu = (const float*)d_in[3];
  const float* bgu = (const float*)d_in[4];
  const float* Wd  = (const float*)d_in[5];
  const float* bd  = (const float*)d_in[6];
  float* out = (float*)d_out;

  int* cnt = (int*)d_ws;                    // 16
  int* off = cnt + 16;                      // 16
  int* e01 = off + 16;                      // 1024
  float* w0f = (float*)(e01 + NT);          // 1024
  float* w1f = w0f + NT;                    // 1024
  int* gtok = (int*)(w1f + NT);             // GROWS
  float* gwt = (float*)(gtok + GROWS);      // GROWS
  unsigned short* Xbf = (unsigned short*)(gwt + GROWS);        // NT*HD bf16
  unsigned short* Gact = Xbf + (size_t)NT * HD;                // GROWS*ED bf16

  k_router<<<NT, 64, 0, stream>>>(x, Wg, bg, bd, e01, w0f, w1f, Xbf, out);
  k_scan<<<1, NT, 0, stream>>>(e01, w0f, w1f, cnt, off, gtok, gwt);
  k_gemm1<<<dim3(32, 8, NEXPERT), 256, 0, stream>>>(Xbf, Wgu, bgu, cnt, off, gtok, Gact);
  k_gemm2<<<dim3(16, 8, 2 * NEXPERT), 256, 0, stream>>>(Gact, Wd, cnt, off, gtok, gwt, out);
}